// Round 9
// baseline (158.577 us; speedup 1.0000x reference)
//
#include <hip/hip_runtime.h>
#include <hip/hip_bf16.h>
#include <math.h>

// Problem dims (fixed by the reference)
#define B_  64
#define S_  512
#define D_  1024
#define E2_ 1024
#define WROW (D_ + E2_)   // 2048, row stride of w_weight
#define NTILES 4          // D_ / BNE (256-wide n-tiles)

typedef __attribute__((ext_vector_type(8))) short bf16x8;
typedef __attribute__((ext_vector_type(4))) float f32x4;
typedef __attribute__((ext_vector_type(8))) unsigned short u16x8;

// round-to-nearest-even f32 -> bf16
__device__ __forceinline__ unsigned short f2bf(float f) {
    unsigned u = __float_as_uint(f);
    u = (u + 0x7FFFu + ((u >> 16) & 1u)) >> 16;
    return (unsigned short)u;
}

__device__ __forceinline__ float bf2f(unsigned short u) {
    return __uint_as_float((unsigned)u << 16);
}

__device__ __forceinline__ void load_lds16(const void* g, void* l) {
    __builtin_amdgcn_global_load_lds(
        (__attribute__((address_space(1))) void*)(void*)g,
        (__attribute__((address_space(3))) void*)l,
        16, 0, 0);
}

// branch-free tanh via v_exp_f32: tanh(x) = sign(x)*(e^{2|x|}-1)/(e^{2|x|}+1)
__device__ __forceinline__ float fast_tanh(float x) {
    float ax = fminf(fabsf(x), 16.0f);                       // tanh(16)==1.0f
    float t  = __builtin_amdgcn_exp2f(ax * 2.8853900817779268f); // e^{2ax}
    float r  = (t - 1.0f) * __builtin_amdgcn_rcpf(t + 1.0f);
    return copysignf(r, x);
}

// ---------------------------------------------------------------------------
// Convert enc (B*S*E2 f32) -> bf16, 8 elems / thread-iter
// ---------------------------------------------------------------------------
__global__ __launch_bounds__(256) void conv_enc_kernel(
        const float* __restrict__ in, unsigned short* __restrict__ out, int n8)
{
    int i = blockIdx.x * 256 + threadIdx.x;
    const int stride = gridDim.x * 256;
    for (; i < n8; i += stride) {
        float4 a = *reinterpret_cast<const float4*>(in + (size_t)i * 8);
        float4 b = *reinterpret_cast<const float4*>(in + (size_t)i * 8 + 4);
        u16x8 o;
        o[0] = f2bf(a.x); o[1] = f2bf(a.y); o[2] = f2bf(a.z); o[3] = f2bf(a.w);
        o[4] = f2bf(b.x); o[5] = f2bf(b.y); o[6] = f2bf(b.z); o[7] = f2bf(b.w);
        *reinterpret_cast<u16x8*>(out + (size_t)i * 8) = o;
    }
}

// ---------------------------------------------------------------------------
// Convert We = w[:, D_:] (strided in w) -> dense bf16 (D_ x E2_)
// ---------------------------------------------------------------------------
__global__ __launch_bounds__(256) void conv_we_kernel(
        const float* __restrict__ w, unsigned short* __restrict__ web)
{
    const int k = blockIdx.x;
    const int j = threadIdx.x * 4;
    float4 a = *reinterpret_cast<const float4*>(w + (size_t)k * WROW + D_ + j);
    ushort4 o;
    o.x = f2bf(a.x); o.y = f2bf(a.y); o.z = f2bf(a.z); o.w = f2bf(a.w);
    *reinterpret_cast<ushort4*>(web + (size_t)k * E2_ + j) = o;
}

// ---------------------------------------------------------------------------
// Kernel A: t[b][k] = sum_d dec[b,d] * W[k,d] + bias[k]   (Wd = w[:, :D]), f32
// ---------------------------------------------------------------------------
__global__ __launch_bounds__(256) void dec_proj_kernel(
        const float* __restrict__ dec,    // (B, D)
        const float* __restrict__ w,      // (D, 2048)
        const float* __restrict__ bias,   // (D)
        float* __restrict__ t)            // (B, D)
{
    __shared__ float wrow[D_];
    __shared__ float red[256];
    const int k = blockIdx.x;
    const int tid = threadIdx.x;

    const float* wr = w + (size_t)k * WROW;
    for (int i = tid; i < D_; i += 256) wrow[i] = wr[i];
    __syncthreads();

    const int b = tid >> 2;
    const int q = tid & 3;
    const float* dp = dec + b * D_ + q * 256;
    const float* wp = wrow + q * 256;
    float acc = 0.f;
    #pragma unroll 8
    for (int i = 0; i < 256; ++i) acc = fmaf(dp[i], wp[i], acc);
    red[tid] = acc;
    __syncthreads();
    if (q == 0) {
        float s = red[tid] + red[tid + 1] + red[tid + 2] + red[tid + 3];
        t[b * D_ + k] = s + bias[k];
    }
}

// ---------------------------------------------------------------------------
// Kernel B: 256x256 tile, BK=64, 8 waves (2 wm x 4 wn), 512 threads.
// 4-PHASE slab pipeline (T3+T4): LDS organized as [buf][kk][256 rows][32 bf16]
// so each K=32 slab is a contiguous 16 KB staging unit (2 gload_lds / thread).
// Phase (kk, ni-half): { ds_read frags | stage one slab of tile kt+1 |
//   setprio + 16 MFMA + setprio } bounded by raw s_barriers; A-frags live in
// regs across the two ni-half phases (24 ds_reads / K-tile total).
// Counted vmcnt(4) at the two slab-consumption edges (end ph1, end ph3):
// exactly the needed oldest 4 loads retire; NEVER vmcnt(0) in steady state.
// Slab-internal swizzle: phys colb = logical colb ^ ((row&3)<<4)  (<=2-way
// bank aliasing = free); staged via inverse-permuted global source.
// XCD m-locality swizzle: 4 n-tile blocks of one m-tile -> same XCD.
// Fused epilogue: tanh + v-dot + cross-wave reduce -> att_part (B*S, 4).
// ---------------------------------------------------------------------------
#define BME 256
#define BNE 256
#define BKE 64
#define KT_ (E2_ / BKE)   // 16 K-tiles

__global__ __launch_bounds__(512, 2) void energy_mfma_kernel(
        const unsigned short* __restrict__ encb,  // (B*S, E2) bf16
        const unsigned short* __restrict__ web,   // (D, E2) bf16
        const float* __restrict__ t,              // (B, D)
        const float* __restrict__ v,              // (D)
        float* __restrict__ att_part)             // (B*S, NTILES)
{
    __shared__ __align__(16) unsigned short As[2][2][256 * 32];  // 64 KB
    __shared__ __align__(16) unsigned short Bs[2][2][256 * 32];  // 64 KB
    __shared__ float tv_s[BNE];
    __shared__ float vv_s[BNE];
    __shared__ float red[4][BME];

    // XCD m-locality swizzle: 512 blocks = 128 mblk x 4 ntile.
    const int g     = blockIdx.x;
    const int mblk  = (g & 7) + 8 * (g >> 5);
    const int ntile = (g >> 3) & 3;

    const int m0 = mblk * BME;
    const int n0 = ntile * BNE;
    const int b  = m0 >> 9;                 // 256-row tile never spans batches
    const int tid = threadIdx.x;
    const int w   = tid >> 6;               // wave 0..7
    const int l   = tid & 63;
    const int wm  = w >> 2;                 // wave row (0..1) -> 128 m-rows
    const int wn  = w & 3;                  // wave col (0..3) -> 64 n-cols

    if (tid < BNE) {
        tv_s[tid] = t[b * D_ + n0 + tid];
        vv_s[tid] = v[n0 + tid];
    }

    // --- staging geometry: slab = 16 KB = 16 chunks of 1 KB; wave w stages
    // chunks 2w, 2w+1. Lane l -> chunk row l>>2, phys colb (l&3)*16.
    // logical colb = phys ^ ((row&3)<<4), row&3 == (l>>2)&3  ->
    // source col (bf16) = ((l&3) ^ ((l>>2)&3)) * 8.
    const int srow = l >> 2;                               // 0..15
    const int scol = ((l & 3) ^ ((l >> 2) & 3)) * 8;       // 0/8/16/24
    const unsigned short* gA = encb + (size_t)m0 * E2_;
    const unsigned short* gB = web  + (size_t)n0 * E2_;

    // --- frag read offsets: row = rX + f*16, phys byte =
    //     row*64 + (((l>>4)*16) ^ ((l&3)<<4))   [row&3 == l&3 for all frags]
    const int rA = wm * 128 + (l & 15);
    const int rB = wn * 64 + (l & 15);
    const int fcol = (((l >> 4) << 4) ^ ((l & 3) << 4));

    f32x4 acc[8][4] = {};

    auto stageA = [&](int bf, int kt, int kk) {
        const int kbase = kt * BKE + kk * 32;
        #pragma unroll
        for (int i = 0; i < 2; ++i) {
            const int c = w * 2 + i;
            const int row = c * 16 + srow;
            load_lds16(gA + (size_t)row * E2_ + kbase + scol,
                       (char*)&As[bf][kk][0] + c * 1024);
        }
    };
    auto stageB = [&](int bf, int kt, int kk) {
        const int kbase = kt * BKE + kk * 32;
        #pragma unroll
        for (int i = 0; i < 2; ++i) {
            const int c = w * 2 + i;
            const int row = c * 16 + srow;
            load_lds16(gB + (size_t)row * E2_ + kbase + scol,
                       (char*)&Bs[bf][kk][0] + c * 1024);
        }
    };

    // prologue: stage tile 0, order Akk0,Bkk0,Akk1,Bkk1 (8 loads/thread)
    stageA(0, 0, 0); stageB(0, 0, 0); stageA(0, 0, 1); stageB(0, 0, 1);
    asm volatile("s_waitcnt vmcnt(4)" ::: "memory");   // Akk0,Bkk0 landed
    __builtin_amdgcn_s_barrier();
    __builtin_amdgcn_sched_barrier(0);

    for (int kt = 0; kt < KT_; ++kt) {
        const int cur = kt & 1;
        const int nxt = cur ^ 1;
        const bool pre = (kt + 1 < KT_);
        bf16x8 a[8], bb[2];

        #pragma unroll
        for (int kk = 0; kk < 2; ++kk) {
            // ---- phase (kk, ni-half 0): 10 ds_read + stage A-slab + 16 MFMA
            #pragma unroll
            for (int mi = 0; mi < 8; ++mi)
                a[mi] = *reinterpret_cast<const bf16x8*>(
                    (const char*)&As[cur][kk][0] + (rA + mi * 16) * 64 + fcol);
            #pragma unroll
            for (int nj = 0; nj < 2; ++nj)
                bb[nj] = *reinterpret_cast<const bf16x8*>(
                    (const char*)&Bs[cur][kk][0] + (rB + nj * 16) * 64 + fcol);
            if (pre) stageA(nxt, kt + 1, kk);
            __builtin_amdgcn_s_setprio(1);
            #pragma unroll
            for (int mi = 0; mi < 8; ++mi) {
                acc[mi][0] = __builtin_amdgcn_mfma_f32_16x16x32_bf16(
                    a[mi], bb[0], acc[mi][0], 0, 0, 0);
                acc[mi][1] = __builtin_amdgcn_mfma_f32_16x16x32_bf16(
                    a[mi], bb[1], acc[mi][1], 0, 0, 0);
            }
            __builtin_amdgcn_s_setprio(0);
            __builtin_amdgcn_sched_barrier(0);
            __builtin_amdgcn_s_barrier();
            __builtin_amdgcn_sched_barrier(0);

            // ---- phase (kk, ni-half 1): 2 ds_read + stage B-slab + 16 MFMA
            #pragma unroll
            for (int nj = 0; nj < 2; ++nj)
                bb[nj] = *reinterpret_cast<const bf16x8*>(
                    (const char*)&Bs[cur][kk][0] + (rB + (2 + nj) * 16) * 64 + fcol);
            if (pre) stageB(nxt, kt + 1, kk);
            __builtin_amdgcn_s_setprio(1);
            #pragma unroll
            for (int mi = 0; mi < 8; ++mi) {
                acc[mi][2] = __builtin_amdgcn_mfma_f32_16x16x32_bf16(
                    a[mi], bb[0], acc[mi][2], 0, 0, 0);
                acc[mi][3] = __builtin_amdgcn_mfma_f32_16x16x32_bf16(
                    a[mi], bb[1], acc[mi][3], 0, 0, 0);
            }
            __builtin_amdgcn_s_setprio(0);
            // slab-edge wait: next consumed slabs' loads are the oldest 4.
            // kk==0 -> tile kt's kk1 slabs; kk==1 -> tile kt+1's kk0 slabs.
            if (pre) {
                asm volatile("s_waitcnt vmcnt(4)" ::: "memory");
            } else if (kk == 0) {
                asm volatile("s_waitcnt vmcnt(0)" ::: "memory");
            }
            __builtin_amdgcn_sched_barrier(0);
            __builtin_amdgcn_s_barrier();
            __builtin_amdgcn_sched_barrier(0);
        }
    }

    // --- epilogue: tanh + v-dot, reduce over n ---
    // D frag mapping: col = l&15, row = (l>>4)*4 + j  [m89-verified]
    #pragma unroll
    for (int mi = 0; mi < 8; ++mi) {
        float P[4] = {0.f, 0.f, 0.f, 0.f};
        #pragma unroll
        for (int ni = 0; ni < 4; ++ni) {
            const int nl = wn * 64 + ni * 16 + (l & 15);
            const float tvv = tv_s[nl];
            const float vvv = vv_s[nl];
            #pragma unroll
            for (int j = 0; j < 4; ++j) {
                float e = fast_tanh(acc[mi][ni][j] + tvv);
                P[j] = fmaf(e, vvv, P[j]);
            }
        }
        #pragma unroll
        for (int j = 0; j < 4; ++j) {
            float p = P[j];
            p += __shfl_xor(p, 1);
            p += __shfl_xor(p, 2);
            p += __shfl_xor(p, 4);
            p += __shfl_xor(p, 8);
            if ((l & 15) == 0)
                red[wn][wm * 128 + mi * 16 + (l >> 4) * 4 + j] = p;
        }
    }
    __syncthreads();
    if (tid < BME)
        att_part[(size_t)(m0 + tid) * NTILES + ntile] =
            (red[0][tid] + red[1][tid]) + (red[2][tid] + red[3][tid]);
}

// ---------------------------------------------------------------------------
// Kernel C: reduce partials + masked softmax over s per batch. One block per b.
// ---------------------------------------------------------------------------
__global__ __launch_bounds__(256) void softmax_kernel(
        const float* __restrict__ att_part,  // (B*S, NTILES)
        const int* __restrict__ mask,        // (B, S)
        float* __restrict__ wout)            // (B, S)
{
    __shared__ float red[256];
    const int b = blockIdx.x;
    const int tid = threadIdx.x;

    float x0 = 0.f, x1 = 0.f;
    #pragma unroll
    for (int p = 0; p < NTILES; ++p) {
        x0 += att_part[(size_t)(b * S_ + tid) * NTILES + p];
        x1 += att_part[(size_t)(b * S_ + 256 + tid) * NTILES + p];
    }
    bool m0v = (mask[b * S_ + tid] != 0);
    bool m1v = (mask[b * S_ + 256 + tid] != 0);
    if (!m0v) x0 = -INFINITY;
    if (!m1v) x1 = -INFINITY;

    float m = fmaxf(x0, x1);
    red[tid] = m;
    __syncthreads();
    for (int o = 128; o > 0; o >>= 1) {
        if (tid < o) red[tid] = fmaxf(red[tid], red[tid + o]);
        __syncthreads();
    }
    m = red[0];
    __syncthreads();

    float e0 = m0v ? expf(x0 - m) : 0.f;
    float e1 = m1v ? expf(x1 - m) : 0.f;
    red[tid] = e0 + e1;
    __syncthreads();
    for (int o = 128; o > 0; o >>= 1) {
        if (tid < o) red[tid] += red[tid + o];
        __syncthreads();
    }
    const float inv = 1.f / red[0];
    wout[b * S_ + tid] = e0 * inv;
    wout[b * S_ + 256 + tid] = e1 * inv;
}

// ---------------------------------------------------------------------------
// Kernel D: out_part[sc][b][e] = sum_{s in chunk sc} wgt[b,s]*encb[b,s,e]
// bf16 enc read (halves traffic), 8 s-chunks of 64, 128 threads (e8 lanes).
// ---------------------------------------------------------------------------
__global__ __launch_bounds__(128) void attout_part_kernel(
        const float* __restrict__ wgt,            // (B, S)
        const unsigned short* __restrict__ encb,  // (B, S, E2) bf16
        float* __restrict__ out_part)             // (8, B, E2)
{
    __shared__ float wsm[64];
    const int b  = blockIdx.y;
    const int sc = blockIdx.x;            // 0..7
    const int tid = threadIdx.x;          // e8 index 0..127
    if (tid < 64) wsm[tid] = wgt[b * S_ + sc * 64 + tid];
    __syncthreads();

    const unsigned short* ep =
        encb + ((size_t)b * S_ + sc * 64) * E2_ + tid * 8;
    float acc[8] = {};
    #pragma unroll 4
    for (int s = 0; s < 64; ++s) {
        u16x8 e8 = *reinterpret_cast<const u16x8*>(ep + (size_t)s * E2_);
        const float ws = wsm[s];
        #pragma unroll
        for (int j = 0; j < 8; ++j)
            acc[j] = fmaf(ws, bf2f((unsigned short)e8[j]), acc[j]);
    }
    float* op = out_part + ((size_t)sc * B_ + b) * E2_ + tid * 8;
    #pragma unroll
    for (int j = 0; j < 8; ++j) op[j] = acc[j];
}

__global__ __launch_bounds__(256) void attout_reduce_kernel(
        const float* __restrict__ out_part,  // (8, B, E2)
        float* __restrict__ out)             // (B, E2)
{
    const int idx = blockIdx.x * 256 + threadIdx.x;   // float4 index
    const int n4 = (B_ * E2_) / 4;
    const float4* p = reinterpret_cast<const float4*>(out_part);
    float4 r = p[idx];
    #pragma unroll
    for (int c = 1; c < 8; ++c) {
        float4 q = p[idx + c * n4];
        r.x += q.x; r.y += q.y; r.z += q.z; r.w += q.w;
    }
    reinterpret_cast<float4*>(out)[idx] = r;
}

// ---------------------------------------------------------------------------
extern "C" void kernel_launch(void* const* d_in, const int* in_sizes, int n_in,
                              void* d_out, int out_size, void* d_ws, size_t ws_size,
                              hipStream_t stream) {
    const float* dec  = (const float*)d_in[0];   // (B, D)
    const float* enc  = (const float*)d_in[1];   // (B, S, E2)
    const int*   mask = (const int*)d_in[2];     // (B, S)
    const float* w    = (const float*)d_in[3];   // (D, D+E2)
    const float* bias = (const float*)d_in[4];   // (D)
    const float* v    = (const float*)d_in[5];   // (D)
    float* out = (float*)d_out;                  // (B, 1, E2)

    // workspace layout
    float* t_buf    = (float*)d_ws;                      // B*D          f32
    float* att_part = t_buf + B_ * D_;                   // B*S*NTILES   f32
    float* wgt_buf  = att_part + B_ * S_ * NTILES;       // B*S          f32
    float* out_part = wgt_buf + B_ * S_;                 // 8*B*E2       f32
    unsigned short* encb = (unsigned short*)(out_part + 8 * B_ * E2_); // bf16
    unsigned short* web  = encb + (size_t)B_ * S_ * E2_;               // bf16

    const int enc_n8 = (B_ * S_ * E2_) / 8;
    conv_enc_kernel<<<4096, 256, 0, stream>>>(enc, encb, enc_n8);
    conv_we_kernel<<<D_, 256, 0, stream>>>(w, web);
    dec_proj_kernel<<<D_, 256, 0, stream>>>(dec, w, bias, t_buf);
    energy_mfma_kernel<<<512, 512, 0, stream>>>(encb, web, t_buf, v, att_part);
    softmax_kernel<<<B_, 256, 0, stream>>>(att_part, mask, wgt_buf);
    attout_part_kernel<<<dim3(8, B_), 128, 0, stream>>>(wgt_buf, encb, out_part);
    attout_reduce_kernel<<<(B_ * E2_ / 4) / 256, 256, 0, stream>>>(out_part, out);
}